// Round 2
// baseline (566.130 us; speedup 1.0000x reference)
//
#include <hip/hip_runtime.h>
#include <stdint.h>

#define H_DIM 2048
#define E_NUM 8
#define D_DIM 2048
#define NTOK 4096

typedef __bf16 bf16x8 __attribute__((ext_vector_type(8)));
typedef float f32x4 __attribute__((ext_vector_type(4)));

__device__ __forceinline__ unsigned short f2bf(float f) {
    union { float f; uint32_t u; } c; c.f = f;
    uint32_t r = (c.u + 0x7FFFu + ((c.u >> 16) & 1u)) >> 16;
    return (unsigned short)r;
}
__device__ __forceinline__ float bf2f(unsigned short h) {
    union { float f; uint32_t u; } c; c.u = ((uint32_t)h) << 16;
    return c.f;
}

// async global->LDS, 16B/lane; LDS dest = wave-uniform base + lane*16.
__device__ __forceinline__ void gl_lds16(const unsigned short* g, unsigned short* l) {
    __builtin_amdgcn_global_load_lds(
        (const __attribute__((address_space(1))) unsigned int*)g,
        (__attribute__((address_space(3))) unsigned int*)l, 16, 0, 0);
}

// ------- K1: router, wave-per-token, fused x -> bf16 conversion -------------
__global__ __launch_bounds__(256) void router_cvt_kernel(
    const float* __restrict__ x, const float* __restrict__ rw,
    const float* __restrict__ rb, int* __restrict__ counts,
    uint32_t* __restrict__ tok, float* __restrict__ gate,
    unsigned short* __restrict__ xb) {
    int t = (blockIdx.x * 256 + threadIdx.x) >> 6;  // token = global wave id
    int lane = threadIdx.x & 63;
    const float* xr = x + (size_t)t * H_DIM;
    unsigned short* xo = xb + (size_t)t * H_DIM;
    float p[E_NUM];
#pragma unroll
    for (int e = 0; e < E_NUM; e++) p[e] = 0.f;
#pragma unroll
    for (int pass = 0; pass < H_DIM / 256; pass++) {
        int h = pass * 256 + lane * 4;
        float4 v = *(const float4*)(xr + h);
        ushort4 o;
        o.x = f2bf(v.x); o.y = f2bf(v.y); o.z = f2bf(v.z); o.w = f2bf(v.w);
        *(ushort4*)(xo + h) = o;
        const float* r0 = rw + (size_t)h * E_NUM;
#pragma unroll
        for (int e = 0; e < E_NUM; e++)
            p[e] += v.x * r0[e] + v.y * r0[e + 8] + v.z * r0[e + 16] + v.w * r0[e + 24];
    }
#pragma unroll
    for (int e = 0; e < E_NUM; e++) {
#pragma unroll
        for (int off = 1; off < 64; off <<= 1) p[e] += __shfl_xor(p[e], off, 64);
    }
    if (lane == 0) {
        float l[E_NUM];
#pragma unroll
        for (int e = 0; e < E_NUM; e++) l[e] = p[e] + rb[e];
        int e0 = 0;
#pragma unroll
        for (int e = 1; e < E_NUM; e++) if (l[e] > l[e0]) e0 = e;
        int e1 = (e0 == 0) ? 1 : 0;
#pragma unroll
        for (int e = 0; e < E_NUM; e++) if (e != e0 && l[e] > l[e1]) e1 = e;
        float g0 = 1.f / (1.f + __expf(l[e1] - l[e0]));
        float g1 = 1.f - g0;
        int p0 = atomicAdd(&counts[e0], 1);
        tok[e0 * NTOK + p0] = (uint32_t)t;
        gate[e0 * NTOK + p0] = g0;
        int p1 = atomicAdd(&counts[e1], 1);
        tok[e1 * NTOK + p1] = (uint32_t)t | (1u << 16);
        gate[e1 * NTOK + p1] = g1;
    }
}

// ------- K2: fused fp32 [K][N] -> bf16 [N][K] transpose for ew + ow ---------
__global__ __launch_bounds__(256) void transpose_cvt_kernel(
    const float* __restrict__ ew, const float* __restrict__ ow,
    unsigned short* __restrict__ ewT) {
    __shared__ unsigned short t[64][136];       // [n][k], +8 pad
    int z = blockIdx.z;
    const float* s = (z < 8) ? (ew + (size_t)z * H_DIM * D_DIM) : ow;
    unsigned short* d = ewT + (size_t)z * H_DIM * D_DIM;
    int n0 = blockIdx.x * 64, k0 = blockIdx.y * 128;
    int tid = threadIdx.x;
    int rr = tid >> 4;          // 0..15
    int c4 = (tid & 15) * 4;    // n offset (floats) in read phase
#pragma unroll
    for (int p = 0; p < 8; p++) {
        int k = p * 16 + rr;
        float4 v = *(const float4*)(s + (size_t)(k0 + k) * D_DIM + n0 + c4);
        t[c4 + 0][k] = f2bf(v.x);
        t[c4 + 1][k] = f2bf(v.y);
        t[c4 + 2][k] = f2bf(v.z);
        t[c4 + 3][k] = f2bf(v.w);
    }
    __syncthreads();
    int kc = (tid & 15) * 8;    // k offset in write phase: 16 lanes x 16B
#pragma unroll
    for (int p = 0; p < 4; p++) {
        int n = p * 16 + rr;
        uint4 v = *(const uint4*)&t[n][kc];
        *(uint4*)(d + (size_t)(n0 + n) * H_DIM + k0 + kc) = v;
    }
}

// ------- K3/K5: m201-geometry 256x256xBK64 8-phase GEMM (T2+T3+T4+T5) -------
// 512 threads = 8 waves (2M x 4N), per-wave output 128x64 -> acc[8][4],
// 16 MFMA per phase (one 64x32 C-quadrant x K=64). LDS 128 KiB dbuf.
// Per K-tile pair: 8 phases; 1 half-tile (128 rows) staged per phase via 2x
// global_load_lds; vmcnt(4) only at phases 4/8 (8 oldest of 12 = next tile).

#define GBAR() __builtin_amdgcn_s_barrier()
#define LGKM0() do { asm volatile("s_waitcnt lgkmcnt(0)" ::: "memory"); \
                     __builtin_amdgcn_sched_barrier(0); } while (0)
#define LGKMH() asm volatile("s_waitcnt lgkmcnt(8)" ::: "memory")
#define VMW4() asm volatile("s_waitcnt vmcnt(4)" ::: "memory")
#define VMW0() asm volatile("s_waitcnt vmcnt(0)" ::: "memory")
#define PRIO1() __builtin_amdgcn_s_setprio(1)
#define PRIO0() __builtin_amdgcn_s_setprio(0)

template <int MOE>
__global__ __launch_bounds__(512, 2) void gemm8p_kernel(
    const unsigned short* __restrict__ Amat,  // xb or comb  [rows][2048] bf16
    const unsigned short* __restrict__ Bmat,  // ewT (per-e) or owT [n][2048] bf16
    const float* __restrict__ bias,           // eb or ob
    const int* __restrict__ counts,
    const uint32_t* __restrict__ tok,
    const float* __restrict__ gate,
    unsigned short* __restrict__ Ybf,         // MOE: [NTOK][2][D] bf16
    float* __restrict__ outF) {               // dense: [NTOK][D] fp32
    constexpr int KD = 2048;
    constexpr int NT = 32;                    // K tiles of 64

    __shared__ unsigned short sA[2][256 * 64];
    __shared__ unsigned short sB[2][256 * 64];
    __shared__ uint32_t tok_s[256];
    __shared__ float gate_s[256];

    const int e = MOE ? blockIdx.z : 0;
    const int cnt = MOE ? counts[e] : NTOK;
    const int m0 = blockIdx.y * 256;
    if (MOE && m0 >= cnt) return;
    const int n0 = blockIdx.x * 256;
    const int tid = threadIdx.x;

    if (MOE) {
        if (tid < 256) {
            int idx = m0 + tid;
            uint32_t tk = 0; float g = 0.f;
            if (idx < cnt) { tk = tok[e * NTOK + idx]; g = gate[e * NTOK + idx]; }
            tok_s[tid] = tk; gate_s[tid] = g;
        }
        __syncthreads();
    }

    const unsigned short* Bp = Bmat + (size_t)e * (size_t)D_DIM * KD;

    // staging map: thread covers row (tid>>3) within each 64-row call,
    // phys chunk tid&7; source chunk pre-swizzled: logical kc at phys kc^(r&7).
    const int rr = tid >> 3;                  // 0..63
    const int swzc = ((tid & 7) ^ (rr & 7)) * 8;
    uint32_t aRow[4], bRow[4];
#pragma unroll
    for (int j = 0; j < 4; j++) {
        int r = j * 64 + rr;
        uint32_t ar = MOE ? (tok_s[r] & 0xFFFFu) : (uint32_t)(m0 + r);
        aRow[j] = ar * (uint32_t)KD + swzc;
        bRow[j] = (uint32_t)(n0 + r) * (uint32_t)KD + swzc;
    }

    const int lane = tid & 63;
    const int wave = tid >> 6;
    const int wm = wave >> 2;   // 0..1 : M strip of 128
    const int wn = wave & 3;    // 0..3 : N strip of 64
    const int row16 = lane & 15;
    const int quad = lane >> 4;
    const char* pA0 = (const char*)&sA[0][0];
    const char* pA1 = (const char*)&sA[1][0];
    const char* pB0 = (const char*)&sB[0][0];
    const char* pB1 = (const char*)&sB[1][0];
    const int baseA = (wm * 128 + row16) * 128;   // bytes, row stride 128B
    const int baseB = (wn * 64 + row16) * 128;
    const int cho0 = ((quad) ^ (lane & 7)) * 16;      // ksub0 swizzled chunk
    const int cho1 = ((4 + quad) ^ (lane & 7)) * 16;  // ksub1
    const int wofs = wave * 512;                      // elems: 1KB per wave

#define STG_A(BUF, HH, T) do { \
        gl_lds16(Amat + aRow[(HH) * 2 + 0] + (T) * 64, &sA[BUF][((HH) * 128 +  0) * 64] + wofs); \
        gl_lds16(Amat + aRow[(HH) * 2 + 1] + (T) * 64, &sA[BUF][((HH) * 128 + 64) * 64] + wofs); } while (0)
#define STG_B(BUF, HH, T) do { \
        gl_lds16(Bp + bRow[(HH) * 2 + 0] + (T) * 64, &sB[BUF][((HH) * 128 +  0) * 64] + wofs); \
        gl_lds16(Bp + bRow[(HH) * 2 + 1] + (T) * 64, &sB[BUF][((HH) * 128 + 64) * 64] + wofs); } while (0)

    bf16x8 af[4][2], b0[2][2], b1[2][2];
    f32x4 acc[8][4];
#pragma unroll
    for (int i = 0; i < 8; i++)
#pragma unroll
        for (int j = 0; j < 4; j++) acc[i][j] = (f32x4)(0.f);

#define LOADA(RS, PBUF) do { _Pragma("unroll") \
        for (int f_ = 0; f_ < 4; f_++) { \
            af[f_][0] = *(const bf16x8*)(PBUF + baseA + ((RS) * 64 + f_ * 16) * 128 + cho0); \
            af[f_][1] = *(const bf16x8*)(PBUF + baseA + ((RS) * 64 + f_ * 16) * 128 + cho1); } } while (0)
#define LOADB(DST, CS, PBUF) do { _Pragma("unroll") \
        for (int c_ = 0; c_ < 2; c_++) { \
            DST[c_][0] = *(const bf16x8*)(PBUF + baseB + ((CS) * 32 + c_ * 16) * 128 + cho0); \
            DST[c_][1] = *(const bf16x8*)(PBUF + baseB + ((CS) * 32 + c_ * 16) * 128 + cho1); } } while (0)
#define MFMAQ(RS, CS, BREG) do { _Pragma("unroll") \
        for (int ks_ = 0; ks_ < 2; ks_++) { _Pragma("unroll") \
            for (int f_ = 0; f_ < 4; f_++) { _Pragma("unroll") \
                for (int c_ = 0; c_ < 2; c_++) \
                    acc[(RS) * 4 + f_][(CS) * 2 + c_] = __builtin_amdgcn_mfma_f32_16x16x32_bf16( \
                        af[f_][ks_], BREG[c_][ks_], acc[(RS) * 4 + f_][(CS) * 2 + c_], 0, 0, 0); } } } while (0)

// Iteration over tile pair (T0 in buf0, T0+1 in buf1). Stage schedule:
// P1: A-h0(T0+1)->b1  P2: A-h1(T0+1)->b1  P3: B-h0(T0+2)->b0  P4: B-h1(T0+2)->b0
// P5: A-h0(T0+2)->b0  P6: A-h1(T0+2)->b0  P7: B-h0(T0+3)->b1  P8: B-h1(T0+3)->b1
// Region-free proof: buf B halves free after P2/P6 barrier; A halves after P3/P7.
// vmcnt(4) at P4: 12 outstanding, oldest 8 = tile T0+1 complete before P5 reads.
#define ITER(T0, SF, VM4, VM8) do { \
        /* P1: Q(0,0) of buf0 */ \
        LOADA(0, pA0); LOADB(b0, 0, pB0); STG_A(1, 0, (T0) + 1); LGKMH(); \
        GBAR(); LGKM0(); PRIO1(); MFMAQ(0, 0, b0); PRIO0(); GBAR(); \
        /* P2: Q(0,1) */ \
        LOADB(b1, 1, pB0); STG_A(1, 1, (T0) + 1); \
        GBAR(); LGKM0(); PRIO1(); MFMAQ(0, 1, b1); PRIO0(); GBAR(); \
        /* P3: Q(1,0) */ \
        LOADA(1, pA0); if (SF) STG_B(0, 0, (T0) + 2); \
        GBAR(); LGKM0(); PRIO1(); MFMAQ(1, 0, b0); PRIO0(); GBAR(); \
        /* P4: Q(1,1) */ \
        if (SF) STG_B(0, 1, (T0) + 2); \
        GBAR(); PRIO1(); MFMAQ(1, 1, b1); PRIO0(); VM4; GBAR(); \
        /* P5: Q(0,0) of buf1 */ \
        LOADA(0, pA1); LOADB(b0, 0, pB1); if (SF) STG_A(0, 0, (T0) + 2); LGKMH(); \
        GBAR(); LGKM0(); PRIO1(); MFMAQ(0, 0, b0); PRIO0(); GBAR(); \
        /* P6: Q(0,1) */ \
        LOADB(b1, 1, pB1); if (SF) STG_A(0, 1, (T0) + 2); \
        GBAR(); LGKM0(); PRIO1(); MFMAQ(0, 1, b1); PRIO0(); GBAR(); \
        /* P7: Q(1,0) */ \
        LOADA(1, pA1); if (SF) STG_B(1, 0, (T0) + 3); \
        GBAR(); LGKM0(); PRIO1(); MFMAQ(1, 0, b0); PRIO0(); GBAR(); \
        /* P8: Q(1,1) */ \
        if (SF) STG_B(1, 1, (T0) + 3); \
        GBAR(); PRIO1(); MFMAQ(1, 1, b1); PRIO0(); VM8; GBAR(); \
    } while (0)

    // prologue: tile0 fully staged (oldest 8 loads) + B(1) in flight (4 loads)
    STG_B(0, 0, 0); STG_B(0, 1, 0); STG_A(0, 0, 0); STG_A(0, 1, 0);
    STG_B(1, 0, 1); STG_B(1, 1, 1);
    VMW4();
    GBAR();

#pragma unroll 1
    for (int it = 0; it < NT / 2 - 1; ++it) {
        ITER(2 * it, 1, VMW4(), VMW4());
    }
    ITER(NT - 2, 0, VMW0(), (void)0);

    // epilogue
    if (MOE) {
#pragma unroll
        for (int f = 0; f < 8; f++) {
            const int rb = wm * 128 + f * 16 + quad * 4;
#pragma unroll
            for (int c = 0; c < 4; c++) {
                const int n = n0 + wn * 64 + c * 16 + row16;
                const float bv = bias[e * D_DIM + n];
#pragma unroll
                for (int r = 0; r < 4; r++) {
                    const int lrow = rb + r;
                    if (m0 + lrow < cnt) {
                        const uint32_t tk = tok_s[lrow];
                        const float g = gate_s[lrow];
                        float v = acc[f][c][r] + bv;
                        float q = 0.7978845608028654f * (v + 0.044715f * v * v * v);
                        float gl = v / (1.f + __expf(-2.f * q));
                        Ybf[((size_t)(tk & 0xFFFFu) * 2 + ((tk >> 16) & 1)) * D_DIM + n] =
                            f2bf(g * gl);
                    }
                }
            }
        }
    } else {
#pragma unroll
        for (int f = 0; f < 8; f++) {
            const int rb = m0 + wm * 128 + f * 16 + quad * 4;
#pragma unroll
            for (int c = 0; c < 4; c++) {
                const int n = n0 + wn * 64 + c * 16 + row16;
                const float bv = bias[n];
#pragma unroll
                for (int r = 0; r < 4; r++)
                    outF[(size_t)(rb + r) * D_DIM + n] = acc[f][c][r] + bv;
            }
        }
    }
#undef STG_A
#undef STG_B
#undef LOADA
#undef LOADB
#undef MFMAQ
#undef ITER
}

// ------- K4: combine slot0+slot1 -> bf16 combined ---------------------------
__global__ __launch_bounds__(256) void combine_kernel(
    const unsigned short* __restrict__ Y, unsigned short* __restrict__ comb) {
    int i = blockIdx.x * 256 + threadIdx.x;  // over NTOK*D/8
    int t = i >> 8;
    int dc = (i & 255) * 8;
    uint4 u0 = *(const uint4*)(Y + (size_t)t * 2 * D_DIM + dc);
    uint4 u1 = *(const uint4*)(Y + ((size_t)t * 2 + 1) * D_DIM + dc);
    uint4 o;
    uint32_t* po = (uint32_t*)&o;
    const uint32_t* p0 = (const uint32_t*)&u0;
    const uint32_t* p1 = (const uint32_t*)&u1;
#pragma unroll
    for (int k = 0; k < 4; k++) {
        uint32_t a = p0[k], b = p1[k];
        float s0 = bf2f((unsigned short)(a & 0xFFFF)) + bf2f((unsigned short)(b & 0xFFFF));
        float s1 = bf2f((unsigned short)(a >> 16)) + bf2f((unsigned short)(b >> 16));
        po[k] = (uint32_t)f2bf(s0) | ((uint32_t)f2bf(s1) << 16);
    }
    *(uint4*)(comb + (size_t)t * D_DIM + dc) = o;
}

extern "C" void kernel_launch(void* const* d_in, const int* in_sizes, int n_in,
                              void* d_out, int out_size, void* d_ws, size_t ws_size,
                              hipStream_t stream) {
    const float* x        = (const float*)d_in[0];  // [4096, 2048]
    const float* router_w = (const float*)d_in[1];  // [2048, 8]
    const float* router_b = (const float*)d_in[2];  // [8]
    const float* expert_w = (const float*)d_in[3];  // [8, 2048, 2048]
    const float* expert_b = (const float*)d_in[4];  // [8, 2048]
    const float* out_w    = (const float*)d_in[5];  // [2048, 2048]
    const float* out_b    = (const float*)d_in[6];  // [2048]
    float* out = (float*)d_out;                     // [4096, 2048]

    char* w = (char*)d_ws;
    int* counts = (int*)w;                          // @0
    uint32_t* tok = (uint32_t*)(w + 1024);
    float* gate = (float*)(w + 1024 + E_NUM * NTOK * 4);
    size_t off = 1024 + (size_t)2 * E_NUM * NTOK * 4;
    unsigned short* xb = (unsigned short*)(w + off);
    off += (size_t)NTOK * H_DIM * 2;
    unsigned short* ewT = (unsigned short*)(w + off);     // [8][D][H]
    off += (size_t)E_NUM * H_DIM * D_DIM * 2;
    unsigned short* owT = (unsigned short*)(w + off);     // contiguous after ewT
    off += (size_t)D_DIM * D_DIM * 2;
    unsigned short* Y = (unsigned short*)(w + off);
    off += (size_t)NTOK * 2 * D_DIM * 2;
    unsigned short* comb = (unsigned short*)(w + off);

    hipMemsetAsync(d_ws, 0, 1024, stream);
    router_cvt_kernel<<<NTOK / 4, 256, 0, stream>>>(x, router_w, router_b,
                                                    counts, tok, gate, xb);
    transpose_cvt_kernel<<<dim3(32, 16, 9), 256, 0, stream>>>(expert_w, out_w, ewT);
    gemm8p_kernel<1><<<dim3(8, 16, 8), 512, 0, stream>>>(
        xb, ewT, expert_b, counts, tok, gate, Y, nullptr);
    combine_kernel<<<NTOK * D_DIM / 8 / 256, 256, 0, stream>>>(Y, comb);
    gemm8p_kernel<0><<<dim3(8, 16, 1), 512, 0, stream>>>(
        comb, owT, out_b, nullptr, nullptr, nullptr, nullptr, out);
}

// Round 3
// 519.761 us; speedup vs baseline: 1.0892x; 1.0892x over previous
//
#include <hip/hip_runtime.h>
#include <stdint.h>

#define H_DIM 2048
#define E_NUM 8
#define D_DIM 2048
#define NTOK 4096

typedef __bf16 bf16x8 __attribute__((ext_vector_type(8)));
typedef float f32x4 __attribute__((ext_vector_type(4)));

__device__ __forceinline__ unsigned short f2bf(float f) {
    union { float f; uint32_t u; } c; c.f = f;
    uint32_t r = (c.u + 0x7FFFu + ((c.u >> 16) & 1u)) >> 16;
    return (unsigned short)r;
}
__device__ __forceinline__ float bf2f(unsigned short h) {
    union { float f; uint32_t u; } c; c.u = ((uint32_t)h) << 16;
    return c.f;
}

// async global->LDS, 16B/lane; LDS dest = wave-uniform base + lane*16.
__device__ __forceinline__ void gl_lds16(const unsigned short* g, unsigned short* l) {
    __builtin_amdgcn_global_load_lds(
        (const __attribute__((address_space(1))) unsigned int*)g,
        (__attribute__((address_space(3))) unsigned int*)l, 16, 0, 0);
}

// opaque LDS read: compiler cannot alias-analyze -> no conservative vmcnt(0)
__device__ __forceinline__ bf16x8 ds_read128(uint32_t addr) {
    bf16x8 r;
    asm volatile("ds_read_b128 %0, %1" : "=v"(r) : "v"(addr));
    return r;
}
#define LGKM0() do { asm volatile("s_waitcnt lgkmcnt(0)" ::: "memory"); \
                     __builtin_amdgcn_sched_barrier(0); } while (0)

// ------- K1: router, wave-per-token, fused x -> bf16 conversion -------------
__global__ __launch_bounds__(256) void router_cvt_kernel(
    const float* __restrict__ x, const float* __restrict__ rw,
    const float* __restrict__ rb, int* __restrict__ counts,
    uint32_t* __restrict__ tok, float* __restrict__ gate,
    unsigned short* __restrict__ xb) {
    int t = (blockIdx.x * 256 + threadIdx.x) >> 6;  // token = global wave id
    int lane = threadIdx.x & 63;
    const float* xr = x + (size_t)t * H_DIM;
    unsigned short* xo = xb + (size_t)t * H_DIM;
    float p[E_NUM];
#pragma unroll
    for (int e = 0; e < E_NUM; e++) p[e] = 0.f;
#pragma unroll
    for (int pass = 0; pass < H_DIM / 256; pass++) {
        int h = pass * 256 + lane * 4;
        float4 v = *(const float4*)(xr + h);
        ushort4 o;
        o.x = f2bf(v.x); o.y = f2bf(v.y); o.z = f2bf(v.z); o.w = f2bf(v.w);
        *(ushort4*)(xo + h) = o;
        const float* r0 = rw + (size_t)h * E_NUM;
#pragma unroll
        for (int e = 0; e < E_NUM; e++)
            p[e] += v.x * r0[e] + v.y * r0[e + 8] + v.z * r0[e + 16] + v.w * r0[e + 24];
    }
#pragma unroll
    for (int e = 0; e < E_NUM; e++) {
#pragma unroll
        for (int off = 1; off < 64; off <<= 1) p[e] += __shfl_xor(p[e], off, 64);
    }
    if (lane == 0) {
        float l[E_NUM];
#pragma unroll
        for (int e = 0; e < E_NUM; e++) l[e] = p[e] + rb[e];
        int e0 = 0;
#pragma unroll
        for (int e = 1; e < E_NUM; e++) if (l[e] > l[e0]) e0 = e;
        int e1 = (e0 == 0) ? 1 : 0;
#pragma unroll
        for (int e = 0; e < E_NUM; e++) if (e != e0 && l[e] > l[e1]) e1 = e;
        float g0 = 1.f / (1.f + __expf(l[e1] - l[e0]));
        float g1 = 1.f - g0;
        int p0 = atomicAdd(&counts[e0], 1);
        tok[e0 * NTOK + p0] = (uint32_t)t;
        gate[e0 * NTOK + p0] = g0;
        int p1 = atomicAdd(&counts[e1], 1);
        tok[e1 * NTOK + p1] = (uint32_t)t | (1u << 16);
        gate[e1 * NTOK + p1] = g1;
    }
}

// ------- K2: fused fp32 [K][N] -> bf16 [N][K] transpose for ew + ow ---------
__global__ __launch_bounds__(256) void transpose_cvt_kernel(
    const float* __restrict__ ew, const float* __restrict__ ow,
    unsigned short* __restrict__ ewT) {
    __shared__ unsigned short t[64][136];       // [n][k], +8 pad
    int z = blockIdx.z;
    const float* s = (z < 8) ? (ew + (size_t)z * H_DIM * D_DIM) : ow;
    unsigned short* d = ewT + (size_t)z * H_DIM * D_DIM;
    int n0 = blockIdx.x * 64, k0 = blockIdx.y * 128;
    int tid = threadIdx.x;
    int rr = tid >> 4;          // 0..15
    int c4 = (tid & 15) * 4;    // n offset (floats) in read phase
#pragma unroll
    for (int p = 0; p < 8; p++) {
        int k = p * 16 + rr;
        float4 v = *(const float4*)(s + (size_t)(k0 + k) * D_DIM + n0 + c4);
        t[c4 + 0][k] = f2bf(v.x);
        t[c4 + 1][k] = f2bf(v.y);
        t[c4 + 2][k] = f2bf(v.z);
        t[c4 + 3][k] = f2bf(v.w);
    }
    __syncthreads();
    int kc = (tid & 15) * 8;    // k offset in write phase: 16 lanes x 16B
#pragma unroll
    for (int p = 0; p < 4; p++) {
        int n = p * 16 + rr;
        uint4 v = *(const uint4*)&t[n][kc];
        *(uint4*)(d + (size_t)(n0 + n) * H_DIM + k0 + kc) = v;
    }
}

// ------- K3/K5: 2-phase double-buffered 128x128xBK64 GEMM -------------------
// r0 structure (4 waves, 2 blocks/CU for cross-block TLP) upgraded with:
// BK=64, LDS double-buffer, stage-issue at step start, ONE __syncthreads per
// step (its implicit vmcnt(0) is the only drain), asm ds_read_b128 fragment
// loads (opaque to alias analysis -> no hidden per-step vmcnt(0) drains).

template <int MOE>
__global__ __launch_bounds__(256, 2) void gemm2p_kernel(
    const unsigned short* __restrict__ Amat,  // xb or comb  [rows][2048] bf16
    const unsigned short* __restrict__ Bmat,  // ewT (per-e) or owT [n][2048] bf16
    const float* __restrict__ bias,           // eb or ob
    const int* __restrict__ counts,
    const uint32_t* __restrict__ tok,
    const float* __restrict__ gate,
    unsigned short* __restrict__ Ybf,         // MOE: [NTOK][2][D] bf16
    float* __restrict__ outF) {               // dense: [NTOK][D] fp32
    constexpr int KD = 2048;
    constexpr int NT = 32;                    // K tiles of 64
    constexpr uint32_t BUFB = 128 * 64 * 2;   // 16 KiB per buffer

    __shared__ unsigned short As[2][128 * 64];
    __shared__ unsigned short Bs[2][128 * 64];
    __shared__ uint32_t tok_s[128];
    __shared__ float gate_s[128];

    const int e = MOE ? blockIdx.z : 0;
    const int cnt = MOE ? counts[e] : NTOK;
    const int m0 = blockIdx.y * 128;
    if (MOE && m0 >= cnt) return;
    const int n0 = blockIdx.x * 128;
    const int tid = threadIdx.x;

    if (MOE) {
        if (tid < 128) {
            int idx = m0 + tid;
            uint32_t tk = 0; float g = 0.f;
            if (idx < cnt) { tk = tok[e * NTOK + idx]; g = gate[e * NTOK + idx]; }
            tok_s[tid] = tk; gate_s[tid] = g;
        }
        __syncthreads();
    }

    const unsigned short* Bp = Bmat + (size_t)e * (size_t)D_DIM * KD;

    // staging: 4 lines each for A/B; line l covers rows l*32 + (tid>>3);
    // phys chunk tid&7 of the 128B row; source chunk pre-swizzled so logical
    // chunk c of row r lands at phys c^(r&7).
    const int rr8 = tid >> 3;                 // 0..31
    const int ch = tid & 7;
    const int swz = (ch ^ (rr8 & 7)) * 8;     // elems
    uint32_t aOff[4], bOff[4];
#pragma unroll
    for (int l = 0; l < 4; l++) {
        int r = l * 32 + rr8;
        uint32_t ar = MOE ? (tok_s[r] & 0xFFFFu) : (uint32_t)(m0 + r);
        aOff[l] = ar * (uint32_t)KD + swz;
        bOff[l] = (uint32_t)(n0 + r) * (uint32_t)KD + swz;
    }

    const int lane = tid & 63;
    const int wave = tid >> 6;
    const int wm = (wave >> 1) * 64;
    const int wn = (wave & 1) * 64;
    const int row16 = lane & 15;
    const int quad = lane >> 4;

    const uint32_t aBase =
        (uint32_t)(uintptr_t)(__attribute__((address_space(3))) unsigned short*)&As[0][0];
    const uint32_t bBase =
        (uint32_t)(uintptr_t)(__attribute__((address_space(3))) unsigned short*)&Bs[0][0];
    uint32_t aFrag[4][2], bFrag[4][2];
#pragma unroll
    for (int i = 0; i < 4; i++)
#pragma unroll
        for (int ks = 0; ks < 2; ks++) {
            uint32_t x = (uint32_t)((((ks * 4 + quad) ^ (row16 & 7)) * 16));
            aFrag[i][ks] = (uint32_t)((wm + i * 16 + row16) * 128) + x;
            bFrag[i][ks] = (uint32_t)((wn + i * 16 + row16) * 128) + x;
        }

    f32x4 acc[4][4];
#pragma unroll
    for (int i = 0; i < 4; i++)
#pragma unroll
        for (int j = 0; j < 4; j++) acc[i][j] = (f32x4)(0.f);

#define STAGE(BUF, T) do { _Pragma("unroll") \
    for (int l_ = 0; l_ < 4; l_++) { \
        gl_lds16(Amat + aOff[l_] + (T) * 64, &As[BUF][(l_ * 32 + wave * 8) * 64]); \
        gl_lds16(Bp + bOff[l_] + (T) * 64, &Bs[BUF][(l_ * 32 + wave * 8) * 64]); \
    } } while (0)

#define COMPUTE(CUR) do { \
    uint32_t ab_ = aBase + (uint32_t)(CUR) * BUFB; \
    uint32_t bb_ = bBase + (uint32_t)(CUR) * BUFB; \
    bf16x8 af_[4][2], bf_[4][2]; \
    _Pragma("unroll") \
    for (int i_ = 0; i_ < 4; i_++) { _Pragma("unroll") \
        for (int k_ = 0; k_ < 2; k_++) { \
            af_[i_][k_] = ds_read128(ab_ + aFrag[i_][k_]); \
            bf_[i_][k_] = ds_read128(bb_ + bFrag[i_][k_]); } } \
    LGKM0(); \
    _Pragma("unroll") \
    for (int k_ = 0; k_ < 2; k_++) { _Pragma("unroll") \
        for (int i_ = 0; i_ < 4; i_++) { _Pragma("unroll") \
            for (int j_ = 0; j_ < 4; j_++) \
                acc[i_][j_] = __builtin_amdgcn_mfma_f32_16x16x32_bf16( \
                    af_[i_][k_], bf_[j_][k_], acc[i_][j_], 0, 0, 0); } } \
    } while (0)

    STAGE(0, 0);
    __syncthreads();                 // implicit vmcnt(0): tile0 resident

    int cur = 0;
#pragma unroll 1
    for (int t = 0; t < NT - 1; ++t) {
        STAGE(cur ^ 1, t + 1);       // issue next tile first: flies during MFMA
        COMPUTE(cur);
        __syncthreads();             // drains stage; reads of cur done by all
        cur ^= 1;
    }
    COMPUTE(cur);                    // last tile, no prefetch

    // epilogue: bias + gelu(tanh form == v*sigmoid(2q)) * gate, scatter to Y
    if (MOE) {
#pragma unroll
        for (int i = 0; i < 4; i++) {
            int rbase = wm + i * 16 + quad * 4;
#pragma unroll
            for (int j = 0; j < 4; j++) {
                int n = n0 + wn + j * 16 + row16;
                float bv = bias[e * D_DIM + n];
#pragma unroll
                for (int r = 0; r < 4; r++) {
                    int lrow = rbase + r;
                    if (m0 + lrow < cnt) {
                        uint32_t tk = tok_s[lrow];
                        float g = gate_s[lrow];
                        float v = acc[i][j][r] + bv;
                        float q = 0.7978845608028654f * (v + 0.044715f * v * v * v);
                        float gl = v / (1.f + __expf(-2.f * q));
                        Ybf[((size_t)(tk & 0xFFFFu) * 2 + ((tk >> 16) & 1)) * D_DIM + n] =
                            f2bf(g * gl);
                    }
                }
            }
        }
    } else {
#pragma unroll
        for (int i = 0; i < 4; i++) {
            int rbase = m0 + wm + i * 16 + quad * 4;
#pragma unroll
            for (int j = 0; j < 4; j++) {
                int n = n0 + wn + j * 16 + row16;
                float bv = bias[n];
#pragma unroll
                for (int r = 0; r < 4; r++)
                    outF[(size_t)(rbase + r) * D_DIM + n] = acc[i][j][r] + bv;
            }
        }
    }
#undef STAGE
#undef COMPUTE
}

// ------- K4: combine slot0+slot1 -> bf16 combined ---------------------------
__global__ __launch_bounds__(256) void combine_kernel(
    const unsigned short* __restrict__ Y, unsigned short* __restrict__ comb) {
    int i = blockIdx.x * 256 + threadIdx.x;  // over NTOK*D/8
    int t = i >> 8;
    int dc = (i & 255) * 8;
    uint4 u0 = *(const uint4*)(Y + (size_t)t * 2 * D_DIM + dc);
    uint4 u1 = *(const uint4*)(Y + ((size_t)t * 2 + 1) * D_DIM + dc);
    uint4 o;
    uint32_t* po = (uint32_t*)&o;
    const uint32_t* p0 = (const uint32_t*)&u0;
    const uint32_t* p1 = (const uint32_t*)&u1;
#pragma unroll
    for (int k = 0; k < 4; k++) {
        uint32_t a = p0[k], b = p1[k];
        float s0 = bf2f((unsigned short)(a & 0xFFFF)) + bf2f((unsigned short)(b & 0xFFFF));
        float s1 = bf2f((unsigned short)(a >> 16)) + bf2f((unsigned short)(b >> 16));
        po[k] = (uint32_t)f2bf(s0) | ((uint32_t)f2bf(s1) << 16);
    }
    *(uint4*)(comb + (size_t)t * D_DIM + dc) = o;
}

extern "C" void kernel_launch(void* const* d_in, const int* in_sizes, int n_in,
                              void* d_out, int out_size, void* d_ws, size_t ws_size,
                              hipStream_t stream) {
    const float* x        = (const float*)d_in[0];  // [4096, 2048]
    const float* router_w = (const float*)d_in[1];  // [2048, 8]
    const float* router_b = (const float*)d_in[2];  // [8]
    const float* expert_w = (const float*)d_in[3];  // [8, 2048, 2048]
    const float* expert_b = (const float*)d_in[4];  // [8, 2048]
    const float* out_w    = (const float*)d_in[5];  // [2048, 2048]
    const float* out_b    = (const float*)d_in[6];  // [2048]
    float* out = (float*)d_out;                     // [4096, 2048]

    char* w = (char*)d_ws;
    int* counts = (int*)w;                          // @0
    uint32_t* tok = (uint32_t*)(w + 1024);
    float* gate = (float*)(w + 1024 + E_NUM * NTOK * 4);
    size_t off = 1024 + (size_t)2 * E_NUM * NTOK * 4;
    unsigned short* xb = (unsigned short*)(w + off);
    off += (size_t)NTOK * H_DIM * 2;
    unsigned short* ewT = (unsigned short*)(w + off);     // [8][D][H]
    off += (size_t)E_NUM * H_DIM * D_DIM * 2;
    unsigned short* owT = (unsigned short*)(w + off);     // contiguous after ewT
    off += (size_t)D_DIM * D_DIM * 2;
    unsigned short* Y = (unsigned short*)(w + off);
    off += (size_t)NTOK * 2 * D_DIM * 2;
    unsigned short* comb = (unsigned short*)(w + off);

    hipMemsetAsync(d_ws, 0, 1024, stream);
    router_cvt_kernel<<<NTOK / 4, 256, 0, stream>>>(x, router_w, router_b,
                                                    counts, tok, gate, xb);
    transpose_cvt_kernel<<<dim3(32, 16, 9), 256, 0, stream>>>(expert_w, out_w, ewT);
    gemm2p_kernel<1><<<dim3(16, 32, 8), 256, 0, stream>>>(
        xb, ewT, expert_b, counts, tok, gate, Y, nullptr);
    combine_kernel<<<NTOK * D_DIM / 8 / 256, 256, 0, stream>>>(Y, comb);
    gemm2p_kernel<0><<<dim3(16, 32), 256, 0, stream>>>(
        comb, owT, out_b, nullptr, nullptr, nullptr, nullptr, out);
}